// Round 2
// baseline (977.630 us; speedup 1.0000x reference)
//
#include <hip/hip_runtime.h>
#include <hip/hip_bf16.h>
#include <stdint.h>
#include <math.h>

// DIM=512, B=16, L=2048, MLP_RATIO=4, GATE_HID=128
#define DIMC 512
#define SEQ  2048
#define NB   16
#define MTOT (NB * SEQ)          // 32768 tokens
#define HID  2048

typedef float v4f __attribute__((ext_vector_type(4)));

__device__ __forceinline__ float bf2f(unsigned short u) {
  union { unsigned int i; float f; } v; v.i = ((unsigned int)u) << 16; return v.f;
}
__device__ __forceinline__ unsigned short f2bf(float f) {
  union { float f; unsigned int i; } v; v.f = f;
  unsigned int r = v.i + 0x7fffu + ((v.i >> 16) & 1u);  // RNE
  return (unsigned short)(r >> 16);
}
__device__ __forceinline__ float gelu_f(float v) {
  return 0.5f * v * (1.f + erff(v * 0.70710678118654752440f));
}
// pack 2 fp32 -> 2 fp8 e4m3 (OCP) in low 16 bits
__device__ __forceinline__ unsigned short pk_fp8(float a, float b) {
  return (unsigned short)__builtin_amdgcn_cvt_pk_fp8_f32(a, b, 0, false);
}
__device__ __forceinline__ unsigned int pk_fp8x4(float a, float b, float c, float d) {
  int lo = __builtin_amdgcn_cvt_pk_fp8_f32(a, b, 0, false);
  return (unsigned int)__builtin_amdgcn_cvt_pk_fp8_f32(c, d, lo, true);
}

typedef __attribute__((address_space(1))) const void cglobal_void;
typedef __attribute__((address_space(3))) void lds_void;
__device__ __forceinline__ void load16_lds(const void* g, void* l) {
  __builtin_amdgcn_global_load_lds((cglobal_void*)g, (lds_void*)l, 16, 0, 0);
}

// ---------------------------------------------------------------------------
// Weight pack: fp32 -> fp8 e4m3, optional transpose. out[r*C+c] = in[c*R+r].
// ---------------------------------------------------------------------------
__global__ __launch_bounds__(256) void pack_w(const float* __restrict__ in,
                                              unsigned char* __restrict__ out,
                                              int R, int C, int trans) {
  int i = blockIdx.x * 256 + threadIdx.x;   // pair index
  if (i * 2 >= R * C) return;
  int r0 = (i * 2) / C, c0 = (i * 2) - r0 * C;
  int r1 = (i * 2 + 1) / C, c1 = (i * 2 + 1) - r1 * C;
  float v0 = trans ? in[(size_t)c0 * R + r0] : in[i * 2];
  float v1 = trans ? in[(size_t)c1 * R + r1] : in[i * 2 + 1];
  *(unsigned short*)(out + (size_t)i * 2) = pk_fp8(v0, v1);
}

// ---------------------------------------------------------------------------
// LN1 + (dwconv3+5+7)/3 + GELU -> g fp8 [M,512]; accumulates gsum[b][d].
// ---------------------------------------------------------------------------
__global__ __launch_bounds__(256) void ln1_conv(
    const float* __restrict__ x, const float* __restrict__ lg, const float* __restrict__ lb,
    const float* __restrict__ w3, const float* __restrict__ b3,
    const float* __restrict__ w5, const float* __restrict__ b5,
    const float* __restrict__ w7, const float* __restrict__ b7,
    unsigned char* __restrict__ gout, float* __restrict__ gsum) {
  __shared__ __align__(16) unsigned short ht[38 * DIMC];
  int blk = blockIdx.x;
  int b = blk >> 6;
  int l0 = (blk & 63) << 5;
  int tid = threadIdx.x, lane = tid & 63, w = tid >> 6;

  for (int r = w; r < 38; r += 4) {
    int l = l0 - 3 + r;
    unsigned short* hrow = ht + r * DIMC;
    if (l < 0 || l >= SEQ) {
      ushort4 z; z.x = z.y = z.z = z.w = 0;
      *(ushort4*)&hrow[lane * 4] = z;
      *(ushort4*)&hrow[256 + lane * 4] = z;
    } else {
      const float4* xp = (const float4*)(x + ((size_t)(b * SEQ + l)) * DIMC);
      float4 v0 = xp[lane], v1 = xp[lane + 64];
      float s = v0.x + v0.y + v0.z + v0.w + v1.x + v1.y + v1.z + v1.w;
      float q = v0.x * v0.x + v0.y * v0.y + v0.z * v0.z + v0.w * v0.w +
                v1.x * v1.x + v1.y * v1.y + v1.z * v1.z + v1.w * v1.w;
#pragma unroll
      for (int o = 32; o > 0; o >>= 1) { s += __shfl_xor(s, o); q += __shfl_xor(q, o); }
      float mu = s * (1.f / 512.f);
      float rs = rsqrtf(q * (1.f / 512.f) - mu * mu + 1e-5f);
      float4 ga = ((const float4*)lg)[lane], gb = ((const float4*)lg)[lane + 64];
      float4 ba = ((const float4*)lb)[lane], bb = ((const float4*)lb)[lane + 64];
      ushort4 o0, o1;
      o0.x = f2bf((v0.x - mu) * rs * ga.x + ba.x);
      o0.y = f2bf((v0.y - mu) * rs * ga.y + ba.y);
      o0.z = f2bf((v0.z - mu) * rs * ga.z + ba.z);
      o0.w = f2bf((v0.w - mu) * rs * ga.w + ba.w);
      o1.x = f2bf((v1.x - mu) * rs * gb.x + bb.x);
      o1.y = f2bf((v1.y - mu) * rs * gb.y + bb.y);
      o1.z = f2bf((v1.z - mu) * rs * gb.z + bb.z);
      o1.w = f2bf((v1.w - mu) * rs * gb.w + bb.w);
      *(ushort4*)&hrow[lane * 4] = o0;
      *(ushort4*)&hrow[256 + lane * 4] = o1;
    }
  }
  __syncthreads();

  int d0 = tid << 1;
  float t3[2][3], t5[2][5], t7[2][7], cb[2];
#pragma unroll
  for (int j = 0; j < 2; j++) {
    int d = d0 + j;
    cb[j] = b3[d] + b5[d] + b7[d];
#pragma unroll
    for (int t = 0; t < 3; t++) t3[j][t] = w3[d * 3 + t];
#pragma unroll
    for (int t = 0; t < 5; t++) t5[j][t] = w5[d * 5 + t];
#pragma unroll
    for (int t = 0; t < 7; t++) t7[j][t] = w7[d * 7 + t];
  }
  float sum0 = 0.f, sum1 = 0.f;
  size_t obase = ((size_t)(b * SEQ + l0)) * DIMC + d0;
  for (int l = 0; l < 32; l++) {
    float h0[7], h1[7];
#pragma unroll
    for (int r = 0; r < 7; r++) {
      unsigned int pk = *(const unsigned int*)&ht[(l + r) * DIMC + d0];
      h0[r] = bf2f((unsigned short)pk);
      h1[r] = bf2f((unsigned short)(pk >> 16));
    }
    float a0 = cb[0], a1 = cb[1];
#pragma unroll
    for (int t = 0; t < 7; t++) { a0 += t7[0][t] * h0[t];     a1 += t7[1][t] * h1[t]; }
#pragma unroll
    for (int t = 0; t < 5; t++) { a0 += t5[0][t] * h0[t + 1]; a1 += t5[1][t] * h1[t + 1]; }
#pragma unroll
    for (int t = 0; t < 3; t++) { a0 += t3[0][t] * h0[t + 2]; a1 += t3[1][t] * h1[t + 2]; }
    a0 *= (1.f / 3.f); a1 *= (1.f / 3.f);
    float g0 = gelu_f(a0), g1 = gelu_f(a1);
    *(unsigned short*)(gout + obase + (size_t)l * DIMC) = pk_fp8(g0, g1);
    sum0 += g0; sum1 += g1;
  }
  atomicAdd(&gsum[b * DIMC + d0], sum0);
  atomicAdd(&gsum[b * DIMC + d0 + 1], sum1);
}

// ---------------------------------------------------------------------------
// Gate (exact fp32): ct = (gsum/L)@wmix^T + bmix; gate = sig(gelu(ct@w1+b1)@w2+b2)
// ---------------------------------------------------------------------------
__global__ __launch_bounds__(128) void gate_kernel(
    const float* __restrict__ gsum, const float* __restrict__ wmix, const float* __restrict__ bmix,
    const float* __restrict__ cg_w1, const float* __restrict__ cg_b1,
    const float* __restrict__ cg_w2, const float* __restrict__ cg_b2,
    float* __restrict__ gate) {
  __shared__ float gbar[512], ct[512], t1[128];
  int b = blockIdx.x, tid = threadIdx.x;
  for (int i = tid; i < 512; i += 128) gbar[i] = gsum[b * 512 + i] * (1.f / (float)SEQ);
  __syncthreads();
  for (int o = tid; o < 512; o += 128) {
    float s = bmix[o];
    const float* wr = wmix + (size_t)o * 512;
    for (int c = 0; c < 512; c++) s += gbar[c] * wr[c];
    ct[o] = s;
  }
  __syncthreads();
  {
    float s = cg_b1[tid];
    for (int c = 0; c < 512; c++) s += ct[c] * cg_w1[c * 128 + tid];
    t1[tid] = gelu_f(s);
  }
  __syncthreads();
  for (int o = tid; o < 512; o += 128) {
    float s = cg_b2[o];
    for (int h = 0; h < 128; h++) s += t1[h] * cg_w2[h * 512 + o];
    gate[b * 512 + o] = 1.f / (1.f + expf(-s));
  }
}

// ---------------------------------------------------------------------------
// LN2: h2 = LN(y) fp8. One wave per token.
// ---------------------------------------------------------------------------
__global__ __launch_bounds__(256) void ln2_kernel(
    const float* __restrict__ y, const float* __restrict__ lg, const float* __restrict__ lb,
    unsigned char* __restrict__ h2) {
  int tok = (blockIdx.x << 2) + (threadIdx.x >> 6);
  int lane = threadIdx.x & 63;
  const float4* yp = (const float4*)(y + ((size_t)tok) * DIMC);
  float4 v0 = yp[lane], v1 = yp[lane + 64];
  float s = v0.x + v0.y + v0.z + v0.w + v1.x + v1.y + v1.z + v1.w;
  float q = v0.x * v0.x + v0.y * v0.y + v0.z * v0.z + v0.w * v0.w +
            v1.x * v1.x + v1.y * v1.y + v1.z * v1.z + v1.w * v1.w;
#pragma unroll
  for (int o = 32; o > 0; o >>= 1) { s += __shfl_xor(s, o); q += __shfl_xor(q, o); }
  float mu = s * (1.f / 512.f);
  float rs = rsqrtf(q * (1.f / 512.f) - mu * mu + 1e-5f);
  float4 ga = ((const float4*)lg)[lane], gb = ((const float4*)lg)[lane + 64];
  float4 ba = ((const float4*)lb)[lane], bb = ((const float4*)lb)[lane + 64];
  unsigned char* hp = h2 + (size_t)tok * DIMC;
  *(unsigned int*)(hp + lane * 4) = pk_fp8x4(
      (v0.x - mu) * rs * ga.x + ba.x, (v0.y - mu) * rs * ga.y + ba.y,
      (v0.z - mu) * rs * ga.z + ba.z, (v0.w - mu) * rs * ga.w + ba.w);
  *(unsigned int*)(hp + 256 + lane * 4) = pk_fp8x4(
      (v1.x - mu) * rs * gb.x + bb.x, (v1.y - mu) * rs * gb.y + bb.y,
      (v1.z - mu) * rs * gb.z + bb.z, (v1.w - mu) * rs * gb.w + bb.w);
}

// ---------------------------------------------------------------------------
// fp8 GEMM, C = A @ B^T (+epilogue). A [M,lda] fp8, B [N,ldb] fp8 (both K-major).
// 128x128 tile, BK=128, 4 waves x 4x4 mfma_f32_16x16x32_fp8_fp8.
// Epilogue goes through a 64x128 fp32 LDS transpose (reuses As/Bs) so global
// I/O is float4/uint coalesced.
// MODE 1: out fp8  = (acc + bias[col]) * gate[(m0>>11)*512 + col]
// MODE 2: out f32  = resid[idx] + (acc + bias[col]) * scale[col]
// MODE 3: out fp8  = gelu(acc + bias[col])
// MODE 4: out f32 += (acc + bias[col]) * scale[col]   (in-place, single pass)
// ---------------------------------------------------------------------------
template <int MODE>
__global__ __launch_bounds__(256) void gemm_bt(
    const unsigned char* __restrict__ A, int lda,
    const unsigned char* __restrict__ B, int ldb,
    const float* __restrict__ bias, const float* __restrict__ scale,
    const float* __restrict__ resid, void* __restrict__ outp,
    int N, int K, const float* __restrict__ gate) {
  __shared__ __align__(16) unsigned char smem[32768];
  unsigned char* As = smem;            // 128 rows x 128 B
  unsigned char* Bs = smem + 16384;    // 128 rows x 128 B
  float* ebuf = (float*)smem;          // epilogue: 64 x 128 fp32

  const int m0 = blockIdx.x * 128, n0 = blockIdx.y * 128;
  const int tid = threadIdx.x, lane = tid & 63, w = tid >> 6;
  const int wm = w >> 1, wn = w & 1, quad = lane >> 4, cn = lane & 15;
  const int srow = lane >> 3, scol = (lane & 7) << 4;

  v4f acc[4][4];
  v4f zero4 = {0.f, 0.f, 0.f, 0.f};
#pragma unroll
  for (int i = 0; i < 4; i++)
#pragma unroll
    for (int j = 0; j < 4; j++) acc[i][j] = zero4;

  for (int k0 = 0; k0 < K; k0 += 128) {
    __syncthreads();
#pragma unroll
    for (int s = 0; s < 4; s++) {
      int seg = (w << 2) + s;                 // 16 segs of 8 rows x 128 B
      int row = (seg << 3) + srow;
      load16_lds(A + (size_t)(m0 + row) * lda + k0 + scol, &As[seg * 1024]);
      load16_lds(B + (size_t)(n0 + row) * ldb + k0 + scol, &Bs[seg * 1024]);
    }
    __syncthreads();
#pragma unroll
    for (int kk = 0; kk < 4; kk++) {
      long af[4], bf[4];
#pragma unroll
      for (int mt = 0; mt < 4; mt++)
        af[mt] = *(const long*)&As[(wm * 64 + mt * 16 + cn) * 128 + kk * 32 + quad * 8];
#pragma unroll
      for (int nt = 0; nt < 4; nt++)
        bf[nt] = *(const long*)&Bs[(wn * 64 + nt * 16 + cn) * 128 + kk * 32 + quad * 8];
#pragma unroll
      for (int mt = 0; mt < 4; mt++)
#pragma unroll
        for (int nt = 0; nt < 4; nt++)
          acc[mt][nt] = __builtin_amdgcn_mfma_f32_16x16x32_fp8_fp8(af[mt], bf[nt], acc[mt][nt], 0, 0, 0);
    }
  }

  // Epilogue via LDS transpose, two 64-row halves.
  const int bb = (MODE == 1) ? (m0 >> 11) : 0;
#pragma unroll
  for (int h = 0; h < 2; h++) {
    __syncthreads();
    if (wm == h) {
#pragma unroll
      for (int mt = 0; mt < 4; mt++)
#pragma unroll
        for (int nt = 0; nt < 4; nt++)
#pragma unroll
          for (int r = 0; r < 4; r++)
            ebuf[(mt * 16 + quad * 4 + r) * 128 + wn * 64 + nt * 16 + cn] = acc[mt][nt][r];
    }
    __syncthreads();
#pragma unroll
    for (int i = 0; i < 8; i++) {
      int fi = (i << 8) + tid;            // 0..2047 float4 index
      int r = fi >> 5, c4 = fi & 31;
      int row = m0 + (h << 6) + r;
      int col = n0 + (c4 << 2);
      const float* e = &ebuf[fi << 2];
      float v0 = e[0], v1 = e[1], v2 = e[2], v3 = e[3];
      float4 bv = *(const float4*)&bias[col];
      v0 += bv.x; v1 += bv.y; v2 += bv.z; v3 += bv.w;
      size_t idx = (size_t)row * N + col;
      if (MODE == 1) {
        float4 gv = *(const float4*)&gate[bb * 512 + col];
        *(unsigned int*)((unsigned char*)outp + idx) =
            pk_fp8x4(v0 * gv.x, v1 * gv.y, v2 * gv.z, v3 * gv.w);
      } else if (MODE == 2) {
        float4 sv = *(const float4*)&scale[col];
        float4 rv = *(const float4*)&resid[idx];
        float4 o; o.x = rv.x + v0 * sv.x; o.y = rv.y + v1 * sv.y;
        o.z = rv.z + v2 * sv.z; o.w = rv.w + v3 * sv.w;
        *(float4*)((float*)outp + idx) = o;
      } else if (MODE == 3) {
        *(unsigned int*)((unsigned char*)outp + idx) =
            pk_fp8x4(gelu_f(v0), gelu_f(v1), gelu_f(v2), gelu_f(v3));
      } else {
        float4 sv = *(const float4*)&scale[col];
        float* op = (float*)outp + idx;
        float4 ov = *(float4*)op;
        float4 o; o.x = ov.x + v0 * sv.x; o.y = ov.y + v1 * sv.y;
        o.z = ov.z + v2 * sv.z; o.w = ov.w + v3 * sv.w;
        *(float4*)op = o;
      }
    }
  }
}

// ---------------------------------------------------------------------------
extern "C" void kernel_launch(void* const* d_in, const int* in_sizes, int n_in,
                              void* d_out, int out_size, void* d_ws, size_t ws_size,
                              hipStream_t stream) {
  (void)in_sizes; (void)n_in; (void)out_size; (void)ws_size;
  const float* x     = (const float*)d_in[0];
  const float* ln1_g = (const float*)d_in[1];
  const float* ln1_b = (const float*)d_in[2];
  const float* w3    = (const float*)d_in[3];
  const float* b3    = (const float*)d_in[4];
  const float* w5    = (const float*)d_in[5];
  const float* b5    = (const float*)d_in[6];
  const float* w7    = (const float*)d_in[7];
  const float* b7    = (const float*)d_in[8];
  const float* wmix  = (const float*)d_in[9];
  const float* bmix  = (const float*)d_in[10];
  const float* cg_w1 = (const float*)d_in[11];
  const float* cg_b1 = (const float*)d_in[12];
  const float* cg_w2 = (const float*)d_in[13];
  const float* cg_b2 = (const float*)d_in[14];
  const float* wout  = (const float*)d_in[15];
  const float* bout  = (const float*)d_in[16];
  const float* ls1   = (const float*)d_in[17];
  const float* ln2_g = (const float*)d_in[18];
  const float* ln2_b = (const float*)d_in[19];
  const float* ffn_w1= (const float*)d_in[20];
  const float* ffn_b1= (const float*)d_in[21];
  const float* ffn_w2= (const float*)d_in[22];
  const float* ffn_b2= (const float*)d_in[23];
  const float* ls2   = (const float*)d_in[24];

  char* ws = (char*)d_ws;
  // workspace layout (bytes) — total ~50 MB
  unsigned char* wmix8 = (unsigned char*)(ws + 0);         // 256KB [512][512]
  unsigned char* wout8 = (unsigned char*)(ws + 262144);    // 256KB [512][512] (wout^T)
  unsigned char* w18   = (unsigned char*)(ws + 524288);    // 1MB   [2048][512] (ffn_w1^T)
  unsigned char* w28   = (unsigned char*)(ws + 1572864);   // 1MB   [512][2048] (ffn_w2^T)
  float*         gsum  = (float*)(ws + 2621440);           // 32KB
  float*         gate  = (float*)(ws + 2654208);           // 32KB
  unsigned char* gbuf  = (unsigned char*)(ws + 3145728);   // 16MB fp8 g
  unsigned char* attn  = (unsigned char*)(ws + 19922944);  // 16MB fp8 attn
  unsigned char* h2buf = (unsigned char*)(ws + 36700160);  // 16MB fp8 h2
  unsigned char* tbuf  = gbuf;  // 32MB t-chunk overlays g+attn (both dead by then)

  hipMemsetAsync(gsum, 0, NB * DIMC * sizeof(float), stream);

  pack_w<<<(512 * 512 / 2 + 255) / 256, 256, 0, stream>>>(wmix,   wmix8, 512, 512, 0);
  pack_w<<<(512 * 512 / 2 + 255) / 256, 256, 0, stream>>>(wout,   wout8, 512, 512, 1);
  pack_w<<<(2048 * 512 / 2 + 255) / 256, 256, 0, stream>>>(ffn_w1, w18, 2048, 512, 1);
  pack_w<<<(2048 * 512 / 2 + 255) / 256, 256, 0, stream>>>(ffn_w2, w28,  512, 2048, 1);

  ln1_conv<<<NB * 64, 256, 0, stream>>>(x, ln1_g, ln1_b, w3, b3, w5, b5, w7, b7, gbuf, gsum);
  gate_kernel<<<NB, 128, 0, stream>>>(gsum, wmix, bmix, cg_w1, cg_b1, cg_w2, cg_b2, gate);

  dim3 grid_d(MTOT / 128, DIMC / 128);  // (256, 4)
  // GEMM1: attn = (g @ wmix^T + bmix) * gate  -> fp8
  gemm_bt<1><<<grid_d, 256, 0, stream>>>(gbuf, 512, wmix8, 512,
                                         bmix, nullptr, nullptr, attn, 512, 512, gate);
  // GEMM2: y1 = x + (attn @ wout + bout) * ls1 -> d_out fp32
  gemm_bt<2><<<grid_d, 256, 0, stream>>>(attn, 512, wout8, 512,
                                         bout, ls1, x, d_out, 512, 512, nullptr);
  // LN2 -> h2 fp8
  ln2_kernel<<<MTOT / 4, 256, 0, stream>>>((const float*)d_out, ln2_g, ln2_b, h2buf);

  // FFN in 2 M-chunks of 16384 tokens: t = gelu(h2@w1^T+b1) fp8 (32MB),
  // then d_out += (t@w2^T + b2) * ls2 with full K=2048 (single RMW pass).
  const int MC = 16384;
  for (int c = 0; c < 2; c++) {
    size_t r0 = (size_t)c * MC;
    dim3 g3(MC / 128, HID / 128);   // (128, 16)
    gemm_bt<3><<<g3, 256, 0, stream>>>(h2buf + r0 * 512, 512, w18, 512,
                                       ffn_b1, nullptr, nullptr, tbuf, HID, 512, nullptr);
    dim3 g4(MC / 128, DIMC / 128);  // (128, 4)
    gemm_bt<4><<<g4, 256, 0, stream>>>(tbuf, 2048, w28, 2048,
                                       ffn_b2, ls2, nullptr,
                                       (float*)d_out + r0 * 512, 512, 2048, nullptr);
  }
}

// Round 4
// 551.275 us; speedup vs baseline: 1.7734x; 1.7734x over previous
//
#include <hip/hip_runtime.h>
#include <hip/hip_bf16.h>
#include <stdint.h>
#include <math.h>

// DIM=512, B=16, L=2048, MLP_RATIO=4, GATE_HID=128
#define DIMC 512
#define SEQ  2048
#define NB   16
#define MTOT (NB * SEQ)          // 32768 tokens
#define HID  2048

// All fp8 GEMM-operand buffers are stored XOR-swizzled in global memory:
//   buf[row][c ^ ((row&7)<<4)] = true[row][c]
// so global_load_lds staging can use the identity lane mapping (m97-proven)
// while LDS fragment reads stay bank-conflict-free (R3's reader).
#define SWZ(row) (((row) & 7) << 4)

typedef float v4f __attribute__((ext_vector_type(4)));

__device__ __forceinline__ float bf2f(unsigned short u) {
  union { unsigned int i; float f; } v; v.i = ((unsigned int)u) << 16; return v.f;
}
__device__ __forceinline__ unsigned short f2bf(float f) {
  union { float f; unsigned int i; } v; v.f = f;
  unsigned int r = v.i + 0x7fffu + ((v.i >> 16) & 1u);  // RNE
  return (unsigned short)(r >> 16);
}
__device__ __forceinline__ float gelu_f(float v) {
  return 0.5f * v * (1.f + erff(v * 0.70710678118654752440f));
}
// pack fp32 -> fp8 e4m3 (OCP)
__device__ __forceinline__ unsigned short pk_fp8(float a, float b) {
  return (unsigned short)__builtin_amdgcn_cvt_pk_fp8_f32(a, b, 0, false);
}
__device__ __forceinline__ unsigned int pk_fp8x4(float a, float b, float c, float d) {
  int lo = __builtin_amdgcn_cvt_pk_fp8_f32(a, b, 0, false);
  return (unsigned int)__builtin_amdgcn_cvt_pk_fp8_f32(c, d, lo, true);
}

typedef __attribute__((address_space(1))) const void cglobal_void;
typedef __attribute__((address_space(3))) void lds_void;
__device__ __forceinline__ void load16_lds(const void* g, void* l) {
  __builtin_amdgcn_global_load_lds((cglobal_void*)g, (lds_void*)l, 16, 0, 0);
}

// ---------------------------------------------------------------------------
// Weight pack: fp32 -> fp8 e4m3, optional transpose, swizzled destination.
// Logical out[r][c] = in[c*R+r] (trans) or in[r*C+c]; stored at c ^ SWZ(r).
// ---------------------------------------------------------------------------
__global__ __launch_bounds__(256) void pack_w(const float* __restrict__ in,
                                              unsigned char* __restrict__ out,
                                              int R, int C, int trans) {
  int i = blockIdx.x * 256 + threadIdx.x;   // pair index (c even)
  if (i * 2 >= R * C) return;
  int r = (i * 2) / C, c = (i * 2) - r * C;
  float v0, v1;
  if (trans) { v0 = in[(size_t)c * R + r]; v1 = in[(size_t)(c + 1) * R + r]; }
  else       { v0 = in[(size_t)r * C + c]; v1 = in[(size_t)r * C + c + 1]; }
  *(unsigned short*)(out + (size_t)r * C + (c ^ SWZ(r))) = pk_fp8(v0, v1);
}

// ---------------------------------------------------------------------------
// LN1 + (dwconv3+5+7)/3 + GELU -> g fp8 [M,512] (swizzled); accumulates gsum.
// ---------------------------------------------------------------------------
__global__ __launch_bounds__(256) void ln1_conv(
    const float* __restrict__ x, const float* __restrict__ lg, const float* __restrict__ lb,
    const float* __restrict__ w3, const float* __restrict__ b3,
    const float* __restrict__ w5, const float* __restrict__ b5,
    const float* __restrict__ w7, const float* __restrict__ b7,
    unsigned char* __restrict__ gout, float* __restrict__ gsum) {
  __shared__ __align__(16) unsigned short ht[38 * DIMC];
  int blk = blockIdx.x;
  int b = blk >> 6;
  int l0 = (blk & 63) << 5;
  int tid = threadIdx.x, lane = tid & 63, w = tid >> 6;

  for (int r = w; r < 38; r += 4) {
    int l = l0 - 3 + r;
    unsigned short* hrow = ht + r * DIMC;
    if (l < 0 || l >= SEQ) {
      ushort4 z; z.x = z.y = z.z = z.w = 0;
      *(ushort4*)&hrow[lane * 4] = z;
      *(ushort4*)&hrow[256 + lane * 4] = z;
    } else {
      const float4* xp = (const float4*)(x + ((size_t)(b * SEQ + l)) * DIMC);
      float4 v0 = xp[lane], v1 = xp[lane + 64];
      float s = v0.x + v0.y + v0.z + v0.w + v1.x + v1.y + v1.z + v1.w;
      float q = v0.x * v0.x + v0.y * v0.y + v0.z * v0.z + v0.w * v0.w +
                v1.x * v1.x + v1.y * v1.y + v1.z * v1.z + v1.w * v1.w;
#pragma unroll
      for (int o = 32; o > 0; o >>= 1) { s += __shfl_xor(s, o); q += __shfl_xor(q, o); }
      float mu = s * (1.f / 512.f);
      float rs = rsqrtf(q * (1.f / 512.f) - mu * mu + 1e-5f);
      float4 ga = ((const float4*)lg)[lane], gb = ((const float4*)lg)[lane + 64];
      float4 ba = ((const float4*)lb)[lane], bb = ((const float4*)lb)[lane + 64];
      ushort4 o0, o1;
      o0.x = f2bf((v0.x - mu) * rs * ga.x + ba.x);
      o0.y = f2bf((v0.y - mu) * rs * ga.y + ba.y);
      o0.z = f2bf((v0.z - mu) * rs * ga.z + ba.z);
      o0.w = f2bf((v0.w - mu) * rs * ga.w + ba.w);
      o1.x = f2bf((v1.x - mu) * rs * gb.x + bb.x);
      o1.y = f2bf((v1.y - mu) * rs * gb.y + bb.y);
      o1.z = f2bf((v1.z - mu) * rs * gb.z + bb.z);
      o1.w = f2bf((v1.w - mu) * rs * gb.w + bb.w);
      *(ushort4*)&hrow[lane * 4] = o0;
      *(ushort4*)&hrow[256 + lane * 4] = o1;
    }
  }
  __syncthreads();

  int d0 = tid << 1;
  float t3[2][3], t5[2][5], t7[2][7], cb[2];
#pragma unroll
  for (int j = 0; j < 2; j++) {
    int d = d0 + j;
    cb[j] = b3[d] + b5[d] + b7[d];
#pragma unroll
    for (int t = 0; t < 3; t++) t3[j][t] = w3[d * 3 + t];
#pragma unroll
    for (int t = 0; t < 5; t++) t5[j][t] = w5[d * 5 + t];
#pragma unroll
    for (int t = 0; t < 7; t++) t7[j][t] = w7[d * 7 + t];
  }
  float sum0 = 0.f, sum1 = 0.f;
  size_t rbase = ((size_t)(b * SEQ + l0)) * DIMC;
  for (int l = 0; l < 32; l++) {
    float h0[7], h1[7];
#pragma unroll
    for (int r = 0; r < 7; r++) {
      unsigned int pk = *(const unsigned int*)&ht[(l + r) * DIMC + d0];
      h0[r] = bf2f((unsigned short)pk);
      h1[r] = bf2f((unsigned short)(pk >> 16));
    }
    float a0 = cb[0], a1 = cb[1];
#pragma unroll
    for (int t = 0; t < 7; t++) { a0 += t7[0][t] * h0[t];     a1 += t7[1][t] * h1[t]; }
#pragma unroll
    for (int t = 0; t < 5; t++) { a0 += t5[0][t] * h0[t + 1]; a1 += t5[1][t] * h1[t + 1]; }
#pragma unroll
    for (int t = 0; t < 3; t++) { a0 += t3[0][t] * h0[t + 2]; a1 += t3[1][t] * h1[t + 2]; }
    a0 *= (1.f / 3.f); a1 *= (1.f / 3.f);
    float g0 = gelu_f(a0), g1 = gelu_f(a1);
    // row = b*SEQ + l0 + l; row&7 == l&7 (l0 multiple of 32)
    *(unsigned short*)(gout + rbase + (size_t)l * DIMC + (d0 ^ SWZ(l))) = pk_fp8(g0, g1);
    sum0 += g0; sum1 += g1;
  }
  atomicAdd(&gsum[b * DIMC + d0], sum0);
  atomicAdd(&gsum[b * DIMC + d0 + 1], sum1);
}

// ---------------------------------------------------------------------------
// Gate (exact fp32): ct = (gsum/L)@wmix^T + bmix; gate = sig(gelu(ct@w1+b1)@w2+b2)
// ---------------------------------------------------------------------------
__global__ __launch_bounds__(128) void gate_kernel(
    const float* __restrict__ gsum, const float* __restrict__ wmix, const float* __restrict__ bmix,
    const float* __restrict__ cg_w1, const float* __restrict__ cg_b1,
    const float* __restrict__ cg_w2, const float* __restrict__ cg_b2,
    float* __restrict__ gate) {
  __shared__ float gbar[512], ct[512], t1[128];
  int b = blockIdx.x, tid = threadIdx.x;
  for (int i = tid; i < 512; i += 128) gbar[i] = gsum[b * 512 + i] * (1.f / (float)SEQ);
  __syncthreads();
  for (int o = tid; o < 512; o += 128) {
    float s = bmix[o];
    const float* wr = wmix + (size_t)o * 512;
    for (int c = 0; c < 512; c++) s += gbar[c] * wr[c];
    ct[o] = s;
  }
  __syncthreads();
  {
    float s = cg_b1[tid];
    for (int c = 0; c < 512; c++) s += ct[c] * cg_w1[c * 128 + tid];
    t1[tid] = gelu_f(s);
  }
  __syncthreads();
  for (int o = tid; o < 512; o += 128) {
    float s = cg_b2[o];
    for (int h = 0; h < 128; h++) s += t1[h] * cg_w2[h * 512 + o];
    gate[b * 512 + o] = 1.f / (1.f + expf(-s));
  }
}

// ---------------------------------------------------------------------------
// LN2: h2 = LN(y) fp8 (swizzled). One wave per token.
// ---------------------------------------------------------------------------
__global__ __launch_bounds__(256) void ln2_kernel(
    const float* __restrict__ y, const float* __restrict__ lg, const float* __restrict__ lb,
    unsigned char* __restrict__ h2) {
  int tok = (blockIdx.x << 2) + (threadIdx.x >> 6);
  int lane = threadIdx.x & 63;
  const float4* yp = (const float4*)(y + ((size_t)tok) * DIMC);
  float4 v0 = yp[lane], v1 = yp[lane + 64];
  float s = v0.x + v0.y + v0.z + v0.w + v1.x + v1.y + v1.z + v1.w;
  float q = v0.x * v0.x + v0.y * v0.y + v0.z * v0.z + v0.w * v0.w +
            v1.x * v1.x + v1.y * v1.y + v1.z * v1.z + v1.w * v1.w;
#pragma unroll
  for (int o = 32; o > 0; o >>= 1) { s += __shfl_xor(s, o); q += __shfl_xor(q, o); }
  float mu = s * (1.f / 512.f);
  float rs = rsqrtf(q * (1.f / 512.f) - mu * mu + 1e-5f);
  float4 ga = ((const float4*)lg)[lane], gb = ((const float4*)lg)[lane + 64];
  float4 ba = ((const float4*)lb)[lane], bb = ((const float4*)lb)[lane + 64];
  unsigned char* hp = h2 + (size_t)tok * DIMC;
  int sw = SWZ(tok);
  *(unsigned int*)(hp + ((lane * 4) ^ sw)) = pk_fp8x4(
      (v0.x - mu) * rs * ga.x + ba.x, (v0.y - mu) * rs * ga.y + ba.y,
      (v0.z - mu) * rs * ga.z + ba.z, (v0.w - mu) * rs * ga.w + ba.w);
  *(unsigned int*)(hp + (256 + ((lane * 4) ^ sw))) = pk_fp8x4(
      (v1.x - mu) * rs * gb.x + bb.x, (v1.y - mu) * rs * gb.y + bb.y,
      (v1.z - mu) * rs * gb.z + bb.z, (v1.w - mu) * rs * gb.w + bb.w);
}

// ---------------------------------------------------------------------------
// fp8 GEMM, C = A @ B^T (+epilogue). A [M,lda], B [N,ldb] fp8, K-major,
// both stored XOR-swizzled (SWZ). 128x128 tile, BK=128, 4 waves x 4x4
// mfma_f32_16x16x32_fp8_fp8. Staging = identity global_load_lds (m97 pattern);
// LDS fragment reads unswizzle with pcol = kcol ^ SWZ(row) -> conflict-free.
// MODE 1: out fp8(swz) = (acc + bias[col]) * gate[(m0>>11)*512 + col]
// MODE 2: out f32      = resid[idx] + (acc + bias[col]) * scale[col]
// MODE 3: out fp8(swz) = gelu(acc + bias[col])
// MODE 4: out f32     += (acc + bias[col]) * scale[col]   (in-place RMW)
// ---------------------------------------------------------------------------
template <int MODE>
__global__ __launch_bounds__(256) void gemm_bt(
    const unsigned char* __restrict__ A, int lda,
    const unsigned char* __restrict__ B, int ldb,
    const float* __restrict__ bias, const float* __restrict__ scale,
    const float* __restrict__ resid, void* __restrict__ outp,
    int N, int K, const float* __restrict__ gate) {
  __shared__ __align__(16) unsigned char smem[32768];
  unsigned char* As = smem;            // 128 rows x 128 B (swizzled image)
  unsigned char* Bs = smem + 16384;    // 128 rows x 128 B (swizzled image)
  float* ebuf = (float*)smem;          // epilogue: 64 x 128 fp32

  const int m0 = blockIdx.x * 128, n0 = blockIdx.y * 128;
  const int tid = threadIdx.x, lane = tid & 63, w = tid >> 6;
  const int wm = w >> 1, wn = w & 1, quad = lane >> 4, cn = lane & 15;
  const int srow = lane >> 3;
  const int scol = (lane & 7) << 4;         // identity staging (m97-proven)
  const int rswz = SWZ(cn);                 // reader-side unswizzle (row&7 == cn&7)

  v4f acc[4][4];
  v4f zero4 = {0.f, 0.f, 0.f, 0.f};
#pragma unroll
  for (int i = 0; i < 4; i++)
#pragma unroll
    for (int j = 0; j < 4; j++) acc[i][j] = zero4;

  for (int k0 = 0; k0 < K; k0 += 128) {
    __syncthreads();
#pragma unroll
    for (int s = 0; s < 4; s++) {
      int seg = (w << 2) + s;                 // 16 segs of 8 rows x 128 B
      int row = (seg << 3) + srow;
      load16_lds(A + (size_t)(m0 + row) * lda + k0 + scol, &As[seg * 1024]);
      load16_lds(B + (size_t)(n0 + row) * ldb + k0 + scol, &Bs[seg * 1024]);
    }
    __syncthreads();
#pragma unroll
    for (int kk = 0; kk < 4; kk++) {
      long af[4], bf[4];
      int pcol = ((kk << 5) + (quad << 3)) ^ rswz;   // physical col of 8B chunk
#pragma unroll
      for (int mt = 0; mt < 4; mt++)
        af[mt] = *(const long*)&As[(wm * 64 + mt * 16 + cn) * 128 + pcol];
#pragma unroll
      for (int nt = 0; nt < 4; nt++)
        bf[nt] = *(const long*)&Bs[(wn * 64 + nt * 16 + cn) * 128 + pcol];
#pragma unroll
      for (int mt = 0; mt < 4; mt++)
#pragma unroll
        for (int nt = 0; nt < 4; nt++)
          acc[mt][nt] = __builtin_amdgcn_mfma_f32_16x16x32_fp8_fp8(af[mt], bf[nt], acc[mt][nt], 0, 0, 0);
    }
  }

  // Epilogue via LDS transpose, two 64-row halves.
  const int bb = (MODE == 1) ? (m0 >> 11) : 0;
#pragma unroll
  for (int h = 0; h < 2; h++) {
    __syncthreads();
    if (wm == h) {
#pragma unroll
      for (int mt = 0; mt < 4; mt++)
#pragma unroll
        for (int nt = 0; nt < 4; nt++)
#pragma unroll
          for (int r = 0; r < 4; r++)
            ebuf[(mt * 16 + quad * 4 + r) * 128 + wn * 64 + nt * 16 + cn] = acc[mt][nt][r];
    }
    __syncthreads();
#pragma unroll
    for (int i = 0; i < 8; i++) {
      int fi = (i << 8) + tid;            // 0..2047 float4 index
      int r = fi >> 5, c4 = fi & 31;
      int row = m0 + (h << 6) + r;
      int col = n0 + (c4 << 2);
      const float* e = &ebuf[fi << 2];
      float v0 = e[0], v1 = e[1], v2 = e[2], v3 = e[3];
      float4 bv = *(const float4*)&bias[col];
      v0 += bv.x; v1 += bv.y; v2 += bv.z; v3 += bv.w;
      size_t idx = (size_t)row * N + col;
      // fp8 outputs are stored swizzled (they feed the next GEMM's A operand)
      size_t sidx = (size_t)row * N + (col ^ SWZ(row));
      if (MODE == 1) {
        float4 gv = *(const float4*)&gate[bb * 512 + col];
        *(unsigned int*)((unsigned char*)outp + sidx) =
            pk_fp8x4(v0 * gv.x, v1 * gv.y, v2 * gv.z, v3 * gv.w);
      } else if (MODE == 2) {
        float4 sv = *(const float4*)&scale[col];
        float4 rv = *(const float4*)&resid[idx];
        float4 o; o.x = rv.x + v0 * sv.x; o.y = rv.y + v1 * sv.y;
        o.z = rv.z + v2 * sv.z; o.w = rv.w + v3 * sv.w;
        *(float4*)((float*)outp + idx) = o;
      } else if (MODE == 3) {
        *(unsigned int*)((unsigned char*)outp + sidx) =
            pk_fp8x4(gelu_f(v0), gelu_f(v1), gelu_f(v2), gelu_f(v3));
      } else {
        float4 sv = *(const float4*)&scale[col];
        float* op = (float*)outp + idx;
        float4 ov = *(float4*)op;
        float4 o; o.x = ov.x + v0 * sv.x; o.y = ov.y + v1 * sv.y;
        o.z = ov.z + v2 * sv.z; o.w = ov.w + v3 * sv.w;
        *(float4*)op = o;
      }
    }
  }
}

// ---------------------------------------------------------------------------
extern "C" void kernel_launch(void* const* d_in, const int* in_sizes, int n_in,
                              void* d_out, int out_size, void* d_ws, size_t ws_size,
                              hipStream_t stream) {
  (void)in_sizes; (void)n_in; (void)out_size; (void)ws_size;
  const float* x     = (const float*)d_in[0];
  const float* ln1_g = (const float*)d_in[1];
  const float* ln1_b = (const float*)d_in[2];
  const float* w3    = (const float*)d_in[3];
  const float* b3    = (const float*)d_in[4];
  const float* w5    = (const float*)d_in[5];
  const float* b5    = (const float*)d_in[6];
  const float* w7    = (const float*)d_in[7];
  const float* b7    = (const float*)d_in[8];
  const float* wmix  = (const float*)d_in[9];
  const float* bmix  = (const float*)d_in[10];
  const float* cg_w1 = (const float*)d_in[11];
  const float* cg_b1 = (const float*)d_in[12];
  const float* cg_w2 = (const float*)d_in[13];
  const float* cg_b2 = (const float*)d_in[14];
  const float* wout  = (const float*)d_in[15];
  const float* bout  = (const float*)d_in[16];
  const float* ls1   = (const float*)d_in[17];
  const float* ln2_g = (const float*)d_in[18];
  const float* ln2_b = (const float*)d_in[19];
  const float* ffn_w1= (const float*)d_in[20];
  const float* ffn_b1= (const float*)d_in[21];
  const float* ffn_w2= (const float*)d_in[22];
  const float* ffn_b2= (const float*)d_in[23];
  const float* ls2   = (const float*)d_in[24];

  char* ws = (char*)d_ws;
  unsigned char* wmix8 = (unsigned char*)(ws + 0);         // 256KB [512][512]
  unsigned char* wout8 = (unsigned char*)(ws + 262144);    // 256KB (wout^T)
  unsigned char* w18   = (unsigned char*)(ws + 524288);    // 1MB   (ffn_w1^T)
  unsigned char* w28   = (unsigned char*)(ws + 1572864);   // 1MB   (ffn_w2^T)
  float*         gsum  = (float*)(ws + 2621440);           // 32KB
  float*         gate  = (float*)(ws + 2654208);           // 32KB
  unsigned char* gbuf  = (unsigned char*)(ws + 3145728);   // 16MB fp8 g
  unsigned char* attn  = (unsigned char*)(ws + 19922944);  // 16MB fp8 attn
  unsigned char* h2buf = (unsigned char*)(ws + 36700160);  // 16MB fp8 h2
  unsigned char* tbuf  = gbuf;  // 32MB t-chunk overlays g+attn (both dead)

  hipMemsetAsync(gsum, 0, NB * DIMC * sizeof(float), stream);

  pack_w<<<(512 * 512 / 2 + 255) / 256, 256, 0, stream>>>(wmix,   wmix8, 512, 512, 0);
  pack_w<<<(512 * 512 / 2 + 255) / 256, 256, 0, stream>>>(wout,   wout8, 512, 512, 1);
  pack_w<<<(2048 * 512 / 2 + 255) / 256, 256, 0, stream>>>(ffn_w1, w18, 2048, 512, 1);
  pack_w<<<(2048 * 512 / 2 + 255) / 256, 256, 0, stream>>>(ffn_w2, w28,  512, 2048, 1);

  ln1_conv<<<NB * 64, 256, 0, stream>>>(x, ln1_g, ln1_b, w3, b3, w5, b5, w7, b7, gbuf, gsum);
  gate_kernel<<<NB, 128, 0, stream>>>(gsum, wmix, bmix, cg_w1, cg_b1, cg_w2, cg_b2, gate);

  dim3 grid_d(MTOT / 128, DIMC / 128);  // (256, 4)
  // GEMM1: attn = (g @ wmix^T + bmix) * gate  -> fp8 (swz)
  gemm_bt<1><<<grid_d, 256, 0, stream>>>(gbuf, 512, wmix8, 512,
                                         bmix, nullptr, nullptr, attn, 512, 512, gate);
  // GEMM2: y1 = x + (attn @ wout + bout) * ls1 -> d_out fp32
  gemm_bt<2><<<grid_d, 256, 0, stream>>>(attn, 512, wout8, 512,
                                         bout, ls1, x, d_out, 512, 512, nullptr);
  // LN2 -> h2 fp8 (swz)
  ln2_kernel<<<MTOT / 4, 256, 0, stream>>>((const float*)d_out, ln2_g, ln2_b, h2buf);

  // FFN in 2 M-chunks: t = gelu(h2@w1^T+b1) fp8 (swz), then d_out += (t@w2^T+b2)*ls2
  const int MC = 16384;
  for (int c = 0; c < 2; c++) {
    size_t r0 = (size_t)c * MC;
    dim3 g3(MC / 128, HID / 128);   // (128, 16)
    gemm_bt<3><<<g3, 256, 0, stream>>>(h2buf + r0 * 512, 512, w18, 512,
                                       ffn_b1, nullptr, nullptr, tbuf, HID, 512, nullptr);
    dim3 g4(MC / 128, DIMC / 128);  // (128, 4)
    gemm_bt<4><<<g4, 256, 0, stream>>>(tbuf, 2048, w28, 2048,
                                       ffn_b2, ls2, nullptr,
                                       (float*)d_out + r0 * 512, 512, 2048, nullptr);
  }
}